// Round 1
// baseline (1089.130 us; speedup 1.0000x reference)
//
#include <hip/hip_runtime.h>

// Problem constants
#define B_   256
#define T_   500
#define DIN  700
#define H_   200
#define NO   400   // H*BR
#define DOUT 35

// GEMM tile config
#define BM 256
#define BN 64
#define BK 16

__device__ __forceinline__ float sigmoidf_(float x) {
    return 1.0f / (1.0f + expf(-x));
}

// Phase 1: Y[t][b][o] = sum_i x[b][t][i] * W_in[o][i] + b_in[o]
// M = B*T rows (m = b*T + t), N = 400 cols, K = 700.
__global__ __launch_bounds__(256) void dh_gemm_in(
    const float* __restrict__ x, const float* __restrict__ Wt,
    const float* __restrict__ bin, float* __restrict__ Y)
{
    __shared__ float As[BK][BM + 4];
    __shared__ float Bs[BK][BN + 4];
    const int tid = threadIdx.x;
    const int tx = tid & 7;    // 0..7  -> cols tx*8..+7
    const int ty = tid >> 3;   // 0..31 -> rows ty*8..+7
    const int m0 = blockIdx.y * BM;
    const int o0 = blockIdx.x * BN;

    float acc[8][8];
    #pragma unroll
    for (int r = 0; r < 8; ++r)
        #pragma unroll
        for (int c = 0; c < 8; ++c) acc[r][c] = 0.0f;

    const int srow = tid >> 2;          // staging row (4 threads/row)
    const int skq  = (tid & 3) << 2;    // staging k offset (float4)

    for (int k0 = 0; k0 < DIN; k0 += BK) {
        // ---- global loads into registers ----
        float4 areg[4];
        #pragma unroll
        for (int i = 0; i < 4; ++i) {
            int idx = tid + i * 256;
            int row = idx >> 2;
            int kq  = (idx & 3) << 2;
            int kg  = k0 + kq;
            if (kg < DIN)
                areg[i] = *reinterpret_cast<const float4*>(&x[(size_t)(m0 + row) * DIN + kg]);
            else
                areg[i] = make_float4(0.f, 0.f, 0.f, 0.f);
        }
        float4 breg;
        {
            int kg = k0 + skq;
            int o  = o0 + srow;
            if (kg < DIN && o < NO)
                breg = *reinterpret_cast<const float4*>(&Wt[(size_t)o * DIN + kg]);
            else
                breg = make_float4(0.f, 0.f, 0.f, 0.f);
        }
        __syncthreads();   // previous iteration's LDS reads done
        // ---- store transposed into LDS ----
        #pragma unroll
        for (int i = 0; i < 4; ++i) {
            int idx = tid + i * 256;
            int row = idx >> 2;
            int kq  = (idx & 3) << 2;
            As[kq + 0][row] = areg[i].x;
            As[kq + 1][row] = areg[i].y;
            As[kq + 2][row] = areg[i].z;
            As[kq + 3][row] = areg[i].w;
        }
        Bs[skq + 0][srow] = breg.x;
        Bs[skq + 1][srow] = breg.y;
        Bs[skq + 2][srow] = breg.z;
        Bs[skq + 3][srow] = breg.w;
        __syncthreads();   // staging visible

        // ---- compute ----
        #pragma unroll
        for (int k = 0; k < BK; ++k) {
            float a[8], bb[8];
            *reinterpret_cast<float4*>(&a[0])  = *reinterpret_cast<const float4*>(&As[k][ty * 8]);
            *reinterpret_cast<float4*>(&a[4])  = *reinterpret_cast<const float4*>(&As[k][ty * 8 + 4]);
            *reinterpret_cast<float4*>(&bb[0]) = *reinterpret_cast<const float4*>(&Bs[k][tx * 8]);
            *reinterpret_cast<float4*>(&bb[4]) = *reinterpret_cast<const float4*>(&Bs[k][tx * 8 + 4]);
            #pragma unroll
            for (int r = 0; r < 8; ++r)
                #pragma unroll
                for (int c = 0; c < 8; ++c)
                    acc[r][c] = fmaf(a[r], bb[c], acc[r][c]);
        }
    }

    // ---- epilogue: add bias, store to Y[t][b][o] ----
    float bo[8];
    #pragma unroll
    for (int c = 0; c < 8; ++c) {
        int o = o0 + tx * 8 + c;
        bo[c] = (o < NO) ? bin[o] : 0.0f;
    }
    const int ob = o0 + tx * 8;
    if (ob < NO) {   // ob multiple of 8 and <400 -> ob<=392 -> ob+7<=399 valid
        #pragma unroll
        for (int r = 0; r < 8; ++r) {
            int m = m0 + ty * 8 + r;
            int b = m / T_;
            int t = m - b * T_;
            float* yrow = &Y[((size_t)t * B_ + b) * NO];
            float4 v0 = make_float4(acc[r][0] + bo[0], acc[r][1] + bo[1],
                                    acc[r][2] + bo[2], acc[r][3] + bo[3]);
            float4 v1 = make_float4(acc[r][4] + bo[4], acc[r][5] + bo[5],
                                    acc[r][6] + bo[6], acc[r][7] + bo[7]);
            *reinterpret_cast<float4*>(&yrow[ob])     = v0;
            *reinterpret_cast<float4*>(&yrow[ob + 4]) = v1;
        }
    }
}

// Phase 2: sequential LIF scan over T per (b,h) neuron. One thread per neuron.
__global__ __launch_bounds__(64) void dh_scan(
    const float* __restrict__ Y, const float* __restrict__ tau_n,
    const float* __restrict__ tau_m, float* __restrict__ counts)
{
    int g = blockIdx.x * 64 + threadIdx.x;   // 0..51199 = b*H + h
    int b = g / H_;
    int h = g - b * H_;
    (void)b;
    float beta0 = sigmoidf_(tau_n[h * 2 + 0]);
    float beta1 = sigmoidf_(tau_n[h * 2 + 1]);
    float alpha = sigmoidf_(tau_m[h]);
    float omb0 = 1.0f - beta0, omb1 = 1.0f - beta1, oma = 1.0f - alpha;
    const float2* Yp = reinterpret_cast<const float2*>(Y);  // (t*B+b)*H + h

    float v = 0.f, i0 = 0.f, i1 = 0.f, cnt = 0.f;
    #pragma unroll 1
    for (int t0 = 0; t0 < T_; t0 += 10) {
        float2 yb[10];
        #pragma unroll
        for (int j = 0; j < 10; ++j)
            yb[j] = Yp[(size_t)(t0 + j) * (B_ * H_) + g];  // 10 loads in flight
        #pragma unroll
        for (int j = 0; j < 10; ++j) {
            i0 = beta0 * i0 + omb0 * yb[j].x;
            i1 = beta1 * i1 + omb1 * yb[j].y;
            float it = i0 + i1;
            v = alpha * v + oma * it;
            if (v >= 1.0f) { v -= 1.0f; cnt += 1.0f; }
        }
    }
    counts[g] = cnt;
}

// Phase 3: out[b][o] = sum_h counts[b][h] * W_out[o][h] + b_out[o]
__global__ __launch_bounds__(64) void dh_out(
    const float* __restrict__ counts, const float* __restrict__ W_out,
    const float* __restrict__ b_out, float* __restrict__ out)
{
    int b = blockIdx.x;
    int o = threadIdx.x;
    if (o >= DOUT) return;
    float acc = b_out[o];
    const float* c = &counts[(size_t)b * H_];
    const float* w = &W_out[(size_t)o * H_];
    #pragma unroll 4
    for (int h = 0; h < H_; ++h)
        acc = fmaf(c[h], w[h], acc);
    out[(size_t)b * DOUT + o] = acc;
}

extern "C" void kernel_launch(void* const* d_in, const int* in_sizes, int n_in,
                              void* d_out, int out_size, void* d_ws, size_t ws_size,
                              hipStream_t stream) {
    const float* x     = (const float*)d_in[0];  // (B,T,DIN)
    const float* W_in  = (const float*)d_in[1];  // (NO,DIN)
    const float* b_in  = (const float*)d_in[2];  // (NO)
    const float* tau_n = (const float*)d_in[3];  // (H,BR)
    const float* tau_m = (const float*)d_in[4];  // (H)
    const float* W_out = (const float*)d_in[5];  // (DOUT,H)
    const float* b_out = (const float*)d_in[6];  // (DOUT)
    float* out = (float*)d_out;                  // (B,DOUT)

    // workspace: Y = 500*256*400 floats (204.8 MB), counts = 51200 floats
    float* Y      = (float*)d_ws;
    float* counts = Y + (size_t)T_ * B_ * NO;

    dim3 g1(7, 500);  // ceil(400/64) x (128000/256)
    dh_gemm_in<<<g1, 256, 0, stream>>>(x, W_in, b_in, Y);
    dh_scan<<<(B_ * H_) / 64, 64, 0, stream>>>(Y, tau_n, tau_m, counts);
    dh_out<<<B_, 64, 0, stream>>>(counts, W_out, b_out, out);
}

// Round 2
// 549.862 us; speedup vs baseline: 1.9807x; 1.9807x over previous
//
#include <hip/hip_runtime.h>

// Problem constants
#define B_   256
#define T_   500
#define DIN  700
#define KP   704      // DIN padded to multiple of 32
#define H_   200
#define NO   400      // H*BR
#define DOUT 35

typedef _Float16 half_t;
typedef __attribute__((ext_vector_type(8))) _Float16 half8;
typedef __attribute__((ext_vector_type(4))) float floatx4;

#define SX 16.0f      // exact pow2 scale for x
#define SW 4096.0f    // exact pow2 scale for W
#define INV_S (1.0f / 65536.0f)

__device__ __forceinline__ float sigmoidf_(float x) {
    return 1.0f / (1.0f + expf(-x));
}

// ---------------------------------------------------------------------------
// Pre-pass: split fp32 -> (hi, lo) fp16 with exact pow2 scaling, K pad to 704.
// src: rows x 700 fp32. dst hi/lo: rows x 704 fp16 (k>=700 zero).
__global__ __launch_bounds__(256) void cvt_split(
    const float* __restrict__ src, half_t* __restrict__ hi,
    half_t* __restrict__ lo, int rows, float scale)
{
    int idx = blockIdx.x * 256 + threadIdx.x;   // (row, quad), quad 0..175
    int row = idx / 176;
    int q   = idx - row * 176;
    if (row >= rows) return;
    float4 v = make_float4(0.f, 0.f, 0.f, 0.f);
    if (q < 175) v = *reinterpret_cast<const float4*>(&src[(size_t)row * DIN + q * 4]);
    float s0 = v.x * scale, s1 = v.y * scale, s2 = v.z * scale, s3 = v.w * scale;
    half_t h0 = (half_t)s0, h1 = (half_t)s1, h2 = (half_t)s2, h3 = (half_t)s3;
    half_t l0 = (half_t)(s0 - (float)h0);
    half_t l1 = (half_t)(s1 - (float)h1);
    half_t l2 = (half_t)(s2 - (float)h2);
    half_t l3 = (half_t)(s3 - (float)h3);
    size_t o = (size_t)row * KP + q * 4;
    half_t hv[4] = {h0, h1, h2, h3};
    half_t lv[4] = {l0, l1, l2, l3};
    *reinterpret_cast<ushort4*>(&hi[o]) = *reinterpret_cast<ushort4*>(hv);
    *reinterpret_cast<ushort4*>(&lo[o]) = *reinterpret_cast<ushort4*>(lv);
}

// ---------------------------------------------------------------------------
// MFMA GEMM: Y[t][b][o] = (1/2^16) * sum_k (Xh+Xl)[m][k] * (Wh+Wl)[o][k] + b_in[o]
// 3-term split: hi*hi + hi*lo + lo*hi. Block tile 256x80, 4 waves of 64x80.
__global__ __launch_bounds__(256) void dh_gemm_f16(
    const half_t* __restrict__ Xh, const half_t* __restrict__ Xl,
    const half_t* __restrict__ Wh, const half_t* __restrict__ Wl,
    const float* __restrict__ bin, float* __restrict__ Y)
{
    __shared__ half_t Ah[256][40], Al[256][40];   // 40-half rows: 16B-aligned, ~2-way banks
    __shared__ half_t Bh[80][40],  Bl[80][40];

    // XCD-bijective swizzle: nwg=2500, 8 XCDs (q=312, r=4)
    int p = blockIdx.x;
    int xcd = p & 7, slot = p >> 3;
    int L = (xcd < 4 ? xcd * 313 : 4 * 313 + (xcd - 4) * 312) + slot;
    int by = L / 5, bx = L - by * 5;
    const int m0 = by * 256, o0 = bx * 80;

    const int tid  = threadIdx.x;
    const int w    = tid >> 6;          // wave 0..3 -> rows w*64..+63
    const int lane = tid & 63;
    const int la   = lane & 15;         // frag row/col
    const int lb   = lane >> 4;         // k-group (0..3) -> k = lb*8 + j

    // staging map: thread covers rows (tid>>2)+{0,64,128,192}, seg = tid&3
    const int srow = tid >> 2, sseg = tid & 3;
    const int brow = srow & 63;         // for B: rows brow+{0,40} handled by tid<160

    floatx4 acc[4][5];
    #pragma unroll
    for (int mf = 0; mf < 4; ++mf)
        #pragma unroll
        for (int nf = 0; nf < 5; ++nf) {
            floatx4 z = {0.f, 0.f, 0.f, 0.f};
            acc[mf][nf] = z;
        }

    half8 rAh[4], rAl[4], rBh[2], rBl[2];

    // issue loads for chunk kc into registers
    auto LOAD = [&](int kc) {
        const int k0 = kc * 32;
        #pragma unroll
        for (int i = 0; i < 4; ++i) {
            size_t g = (size_t)(m0 + srow + i * 64) * KP + k0 + sseg * 8;
            rAh[i] = *reinterpret_cast<const half8*>(&Xh[g]);
            rAl[i] = *reinterpret_cast<const half8*>(&Xl[g]);
        }
        if (tid < 160) {
            #pragma unroll
            for (int i = 0; i < 2; ++i) {
                size_t g = (size_t)(o0 + brow + i * 40) * KP + k0 + sseg * 8;
                rBh[i] = *reinterpret_cast<const half8*>(&Wh[g]);
                rBl[i] = *reinterpret_cast<const half8*>(&Wl[g]);
            }
        }
    };

    LOAD(0);

    for (int kc = 0; kc < 22; ++kc) {
        __syncthreads();   // readers of previous chunk done
        #pragma unroll
        for (int i = 0; i < 4; ++i) {
            *reinterpret_cast<half8*>(&Ah[srow + i * 64][sseg * 8]) = rAh[i];
            *reinterpret_cast<half8*>(&Al[srow + i * 64][sseg * 8]) = rAl[i];
        }
        if (tid < 160) {
            #pragma unroll
            for (int i = 0; i < 2; ++i) {
                *reinterpret_cast<half8*>(&Bh[brow + i * 40][sseg * 8]) = rBh[i];
                *reinterpret_cast<half8*>(&Bl[brow + i * 40][sseg * 8]) = rBl[i];
            }
        }
        __syncthreads();   // staged chunk visible

        if (kc + 1 < 22) LOAD(kc + 1);   // issue next-chunk loads early (T14)

        half8 ah[4], al[4], bh[5], bl[5];
        #pragma unroll
        for (int mf = 0; mf < 4; ++mf) {
            int r = w * 64 + mf * 16 + la;
            ah[mf] = *reinterpret_cast<const half8*>(&Ah[r][lb * 8]);
            al[mf] = *reinterpret_cast<const half8*>(&Al[r][lb * 8]);
        }
        #pragma unroll
        for (int nf = 0; nf < 5; ++nf) {
            int r = nf * 16 + la;
            bh[nf] = *reinterpret_cast<const half8*>(&Bh[r][lb * 8]);
            bl[nf] = *reinterpret_cast<const half8*>(&Bl[r][lb * 8]);
        }
        // three term groups, independent MFMAs interleavable within each
        #pragma unroll
        for (int mf = 0; mf < 4; ++mf)
            #pragma unroll
            for (int nf = 0; nf < 5; ++nf)
                acc[mf][nf] = __builtin_amdgcn_mfma_f32_16x16x32_f16(ah[mf], bh[nf], acc[mf][nf], 0, 0, 0);
        #pragma unroll
        for (int mf = 0; mf < 4; ++mf)
            #pragma unroll
            for (int nf = 0; nf < 5; ++nf)
                acc[mf][nf] = __builtin_amdgcn_mfma_f32_16x16x32_f16(ah[mf], bl[nf], acc[mf][nf], 0, 0, 0);
        #pragma unroll
        for (int mf = 0; mf < 4; ++mf)
            #pragma unroll
            for (int nf = 0; nf < 5; ++nf)
                acc[mf][nf] = __builtin_amdgcn_mfma_f32_16x16x32_f16(al[mf], bh[nf], acc[mf][nf], 0, 0, 0);
    }

    // epilogue: C/D layout col = lane&15, row = (lane>>4)*4 + reg
    float bo[5];
    #pragma unroll
    for (int nf = 0; nf < 5; ++nf) bo[nf] = bin[o0 + nf * 16 + la];

    #pragma unroll
    for (int mf = 0; mf < 4; ++mf) {
        int mbase = m0 + w * 64 + mf * 16 + lb * 4;
        #pragma unroll
        for (int rg = 0; rg < 4; ++rg) {
            int mm = mbase + rg;
            int bb = mm / T_;
            int tt = mm - bb * T_;
            float* yrow = &Y[((size_t)tt * B_ + bb) * NO + o0 + la];
            #pragma unroll
            for (int nf = 0; nf < 5; ++nf)
                yrow[nf * 16] = acc[mf][nf][rg] * INV_S + bo[nf];
        }
    }
}

// ---------------------------------------------------------------------------
// Fallback fp32 GEMM (known-good) if workspace too small for fp16 path.
#define BM 256
#define BN 64
#define BK 16
__global__ __launch_bounds__(256) void dh_gemm_in(
    const float* __restrict__ x, const float* __restrict__ Wt,
    const float* __restrict__ bin, float* __restrict__ Y)
{
    __shared__ float As[BK][BM + 4];
    __shared__ float Bs[BK][BN + 4];
    const int tid = threadIdx.x;
    const int tx = tid & 7;
    const int ty = tid >> 3;
    const int m0 = blockIdx.y * BM;
    const int o0 = blockIdx.x * BN;

    float acc[8][8];
    #pragma unroll
    for (int r = 0; r < 8; ++r)
        #pragma unroll
        for (int c = 0; c < 8; ++c) acc[r][c] = 0.0f;

    const int srow = tid >> 2;
    const int skq  = (tid & 3) << 2;

    for (int k0 = 0; k0 < DIN; k0 += BK) {
        float4 areg[4];
        #pragma unroll
        for (int i = 0; i < 4; ++i) {
            int idx = tid + i * 256;
            int row = idx >> 2;
            int kq  = (idx & 3) << 2;
            int kg  = k0 + kq;
            if (kg < DIN)
                areg[i] = *reinterpret_cast<const float4*>(&x[(size_t)(m0 + row) * DIN + kg]);
            else
                areg[i] = make_float4(0.f, 0.f, 0.f, 0.f);
        }
        float4 breg;
        {
            int kg = k0 + skq;
            int o  = o0 + srow;
            if (kg < DIN && o < NO)
                breg = *reinterpret_cast<const float4*>(&Wt[(size_t)o * DIN + kg]);
            else
                breg = make_float4(0.f, 0.f, 0.f, 0.f);
        }
        __syncthreads();
        #pragma unroll
        for (int i = 0; i < 4; ++i) {
            int idx = tid + i * 256;
            int row = idx >> 2;
            int kq  = (idx & 3) << 2;
            As[kq + 0][row] = areg[i].x;
            As[kq + 1][row] = areg[i].y;
            As[kq + 2][row] = areg[i].z;
            As[kq + 3][row] = areg[i].w;
        }
        Bs[skq + 0][srow] = breg.x;
        Bs[skq + 1][srow] = breg.y;
        Bs[skq + 2][srow] = breg.z;
        Bs[skq + 3][srow] = breg.w;
        __syncthreads();

        #pragma unroll
        for (int k = 0; k < BK; ++k) {
            float a[8], bb[8];
            *reinterpret_cast<float4*>(&a[0])  = *reinterpret_cast<const float4*>(&As[k][ty * 8]);
            *reinterpret_cast<float4*>(&a[4])  = *reinterpret_cast<const float4*>(&As[k][ty * 8 + 4]);
            *reinterpret_cast<float4*>(&bb[0]) = *reinterpret_cast<const float4*>(&Bs[k][tx * 8]);
            *reinterpret_cast<float4*>(&bb[4]) = *reinterpret_cast<const float4*>(&Bs[k][tx * 8 + 4]);
            #pragma unroll
            for (int r = 0; r < 8; ++r)
                #pragma unroll
                for (int c = 0; c < 8; ++c)
                    acc[r][c] = fmaf(a[r], bb[c], acc[r][c]);
        }
    }

    float bo[8];
    #pragma unroll
    for (int c = 0; c < 8; ++c) {
        int o = o0 + tx * 8 + c;
        bo[c] = (o < NO) ? bin[o] : 0.0f;
    }
    const int ob = o0 + tx * 8;
    if (ob < NO) {
        #pragma unroll
        for (int r = 0; r < 8; ++r) {
            int m = m0 + ty * 8 + r;
            int b = m / T_;
            int t = m - b * T_;
            float* yrow = &Y[((size_t)t * B_ + b) * NO];
            float4 v0 = make_float4(acc[r][0] + bo[0], acc[r][1] + bo[1],
                                    acc[r][2] + bo[2], acc[r][3] + bo[3]);
            float4 v1 = make_float4(acc[r][4] + bo[4], acc[r][5] + bo[5],
                                    acc[r][6] + bo[6], acc[r][7] + bo[7]);
            *reinterpret_cast<float4*>(&yrow[ob])     = v0;
            *reinterpret_cast<float4*>(&yrow[ob + 4]) = v1;
        }
    }
}

// ---------------------------------------------------------------------------
// Phase 2: sequential LIF scan over T per (b,h) neuron.
__global__ __launch_bounds__(64) void dh_scan(
    const float* __restrict__ Y, const float* __restrict__ tau_n,
    const float* __restrict__ tau_m, float* __restrict__ counts)
{
    int g = blockIdx.x * 64 + threadIdx.x;   // b*H + h
    int b = g / H_;
    int h = g - b * H_;
    (void)b;
    float beta0 = sigmoidf_(tau_n[h * 2 + 0]);
    float beta1 = sigmoidf_(tau_n[h * 2 + 1]);
    float alpha = sigmoidf_(tau_m[h]);
    float omb0 = 1.0f - beta0, omb1 = 1.0f - beta1, oma = 1.0f - alpha;
    const float2* Yp = reinterpret_cast<const float2*>(Y);

    float v = 0.f, i0 = 0.f, i1 = 0.f, cnt = 0.f;
    #pragma unroll 1
    for (int t0 = 0; t0 < T_; t0 += 10) {
        float2 yb[10];
        #pragma unroll
        for (int j = 0; j < 10; ++j)
            yb[j] = Yp[(size_t)(t0 + j) * (B_ * H_) + g];
        #pragma unroll
        for (int j = 0; j < 10; ++j) {
            i0 = beta0 * i0 + omb0 * yb[j].x;
            i1 = beta1 * i1 + omb1 * yb[j].y;
            float it = i0 + i1;
            v = alpha * v + oma * it;
            if (v >= 1.0f) { v -= 1.0f; cnt += 1.0f; }
        }
    }
    counts[g] = cnt;
}

// Phase 3: out[b][o] = sum_h counts[b][h] * W_out[o][h] + b_out[o]
__global__ __launch_bounds__(64) void dh_out(
    const float* __restrict__ counts, const float* __restrict__ W_out,
    const float* __restrict__ b_out, float* __restrict__ out)
{
    int b = blockIdx.x;
    int o = threadIdx.x;
    if (o >= DOUT) return;
    float acc = b_out[o];
    const float* c = &counts[(size_t)b * H_];
    const float* w = &W_out[(size_t)o * H_];
    #pragma unroll 4
    for (int h = 0; h < H_; ++h)
        acc = fmaf(c[h], w[h], acc);
    out[(size_t)b * DOUT + o] = acc;
}

extern "C" void kernel_launch(void* const* d_in, const int* in_sizes, int n_in,
                              void* d_out, int out_size, void* d_ws, size_t ws_size,
                              hipStream_t stream) {
    const float* x     = (const float*)d_in[0];  // (B,T,DIN)
    const float* W_in  = (const float*)d_in[1];  // (NO,DIN)
    const float* b_in  = (const float*)d_in[2];  // (NO)
    const float* tau_n = (const float*)d_in[3];  // (H,BR)
    const float* tau_m = (const float*)d_in[4];  // (H)
    const float* W_out = (const float*)d_in[5];  // (DOUT,H)
    const float* b_out = (const float*)d_in[6];  // (DOUT)
    float* out = (float*)d_out;                  // (B,DOUT)

    const size_t M = (size_t)B_ * T_;            // 128000
    float* Y      = (float*)d_ws;                // 51.2M floats
    float* counts = Y + M * NO / (size_t)T_ * T_ / (size_t)B_ / 1 * 0 + (size_t)T_ * B_ * NO; // = Y + 51200000
    counts = Y + (size_t)T_ * B_ * NO;

    size_t need_f16 = (size_t)T_ * B_ * NO * 4 + (size_t)B_ * H_ * 4
                    + 2 * (M * KP * 2) + 2 * ((size_t)NO * KP * 2);

    if (ws_size >= need_f16) {
        half_t* Xh = (half_t*)(counts + (size_t)B_ * H_);
        half_t* Xl = Xh + M * KP;
        half_t* Wh = Xl + M * KP;
        half_t* Wl = Wh + (size_t)NO * KP;

        cvt_split<<<(M * 176 + 255) / 256, 256, 0, stream>>>(x, Xh, Xl, (int)M, SX);
        cvt_split<<<(NO * 176 + 255) / 256, 256, 0, stream>>>(W_in, Wh, Wl, NO, SW);
        dh_gemm_f16<<<2500, 256, 0, stream>>>(Xh, Xl, Wh, Wl, b_in, Y);
    } else {
        dim3 g1(7, 500);
        dh_gemm_in<<<g1, 256, 0, stream>>>(x, W_in, b_in, Y);
    }

    dh_scan<<<(B_ * H_) / 64, 64, 0, stream>>>(Y, tau_n, tau_m, counts);
    dh_out<<<B_, 64, 0, stream>>>(counts, W_out, b_out, out);
}

// Round 3
// 424.668 us; speedup vs baseline: 2.5647x; 1.2948x over previous
//
#include <hip/hip_runtime.h>

// Problem constants
#define B_   256
#define T_   500
#define DIN  700
#define KP   704      // DIN padded to multiple of 32 (for W only)
#define H_   200
#define NO   400      // H*BR
#define DOUT 35

typedef _Float16 half_t;
typedef __attribute__((ext_vector_type(8))) _Float16 half8;
typedef __attribute__((ext_vector_type(4))) float floatx4;

#define SX 16.0f      // exact pow2 scale for x
#define SW 4096.0f    // exact pow2 scale for W
#define INV_S (1.0f / 65536.0f)

__device__ __forceinline__ float sigmoidf_(float x) {
    return 1.0f / (1.0f + expf(-x));
}

// ---------------------------------------------------------------------------
// Pre-pass (W only): split fp32 -> (hi, lo) fp16, exact pow2 scale, pad to 704.
__global__ __launch_bounds__(256) void cvt_split(
    const float* __restrict__ src, half_t* __restrict__ hi,
    half_t* __restrict__ lo, int rows, float scale)
{
    int idx = blockIdx.x * 256 + threadIdx.x;   // (row, quad), quad 0..175
    int row = idx / 176;
    int q   = idx - row * 176;
    if (row >= rows) return;
    float4 v = make_float4(0.f, 0.f, 0.f, 0.f);
    if (q < 175) v = *reinterpret_cast<const float4*>(&src[(size_t)row * DIN + q * 4]);
    float s0 = v.x * scale, s1 = v.y * scale, s2 = v.z * scale, s3 = v.w * scale;
    half_t h0 = (half_t)s0, h1 = (half_t)s1, h2 = (half_t)s2, h3 = (half_t)s3;
    half_t l0 = (half_t)(s0 - (float)h0);
    half_t l1 = (half_t)(s1 - (float)h1);
    half_t l2 = (half_t)(s2 - (float)h2);
    half_t l3 = (half_t)(s3 - (float)h3);
    size_t o = (size_t)row * KP + q * 4;
    half_t hv[4] = {h0, h1, h2, h3};
    half_t lv[4] = {l0, l1, l2, l3};
    *reinterpret_cast<ushort4*>(&hi[o]) = *reinterpret_cast<ushort4*>(hv);
    *reinterpret_cast<ushort4*>(&lo[o]) = *reinterpret_cast<ushort4*>(lv);
}

// ---------------------------------------------------------------------------
// Fused MFMA GEMM: reads x fp32, converts to (hi,lo) fp16 in-register, stages
// to LDS, 3-term split-fp16 MFMA (hi*hi + hi*lo + lo*hi), fp32 accumulate.
// Y[t][b][o] = (1/2^16) * sum_k ... + b_in[o]. Block tile 256x80, 4 waves.
__global__ __launch_bounds__(256) void dh_gemm_fused(
    const float* __restrict__ x,
    const half_t* __restrict__ Wh, const half_t* __restrict__ Wl,
    const float* __restrict__ bin, float* __restrict__ Y)
{
    __shared__ half_t Ah[256][40], Al[256][40];   // 40-half rows: 16B-aligned
    __shared__ half_t Bh[80][40],  Bl[80][40];

    // XCD-bijective swizzle: nwg=2500, 8 XCDs (q=312, r=4); 5 consecutive L
    // share an A-panel -> same XCD -> L2 hits on x.
    int p = blockIdx.x;
    int xcd = p & 7, slot = p >> 3;
    int L = (xcd < 4 ? xcd * 313 : 4 * 313 + (xcd - 4) * 312) + slot;
    int by = L / 5, bx = L - by * 5;
    const int m0 = by * 256, o0 = bx * 80;

    const int tid  = threadIdx.x;
    const int w    = tid >> 6;          // wave 0..3 -> rows w*64..+63
    const int lane = tid & 63;
    const int la   = lane & 15;         // frag row/col
    const int lb   = lane >> 4;         // k-group (0..3)

    // staging map: thread covers rows (tid>>2)+{0,64,128,192}, seg = tid&3 (8 elems)
    const int srow = tid >> 2, sseg = tid & 3;
    const int brow = srow & 63;         // B rows brow+{0,40} for tid<160

    floatx4 acc[4][5];
    #pragma unroll
    for (int mf = 0; mf < 4; ++mf)
        #pragma unroll
        for (int nf = 0; nf < 5; ++nf) {
            floatx4 z = {0.f, 0.f, 0.f, 0.f};
            acc[mf][nf] = z;
        }

    float4 rAf[4][2];
    half8 rBh[2], rBl[2];

    auto LOAD = [&](int kc) {
        const int k0 = kc * 32;
        const int kcol = k0 + sseg * 8;
        #pragma unroll
        for (int i = 0; i < 4; ++i) {
            const float* src = &x[(size_t)(m0 + srow + i * 64) * DIN + kcol];
            rAf[i][0] = *reinterpret_cast<const float4*>(src);       // kcol..+3 always < 700
            if (kcol + 8 <= DIN)
                rAf[i][1] = *reinterpret_cast<const float4*>(src + 4);
            else
                rAf[i][1] = make_float4(0.f, 0.f, 0.f, 0.f);          // zero-pad 700..703
        }
        if (tid < 160) {
            #pragma unroll
            for (int i = 0; i < 2; ++i) {
                size_t g = (size_t)(o0 + brow + i * 40) * KP + k0 + sseg * 8;
                rBh[i] = *reinterpret_cast<const half8*>(&Wh[g]);
                rBl[i] = *reinterpret_cast<const half8*>(&Wl[g]);
            }
        }
    };

    LOAD(0);

    for (int kc = 0; kc < 22; ++kc) {
        __syncthreads();   // readers of previous chunk done
        // convert + stage A (hi/lo split; exact pow2 scale)
        #pragma unroll
        for (int i = 0; i < 4; ++i) {
            float vv[8];
            *reinterpret_cast<float4*>(&vv[0]) = rAf[i][0];
            *reinterpret_cast<float4*>(&vv[4]) = rAf[i][1];
            half8 hh, ll;
            #pragma unroll
            for (int j = 0; j < 8; ++j) {
                float s = vv[j] * SX;
                half_t h = (half_t)s;
                hh[j] = h;
                ll[j] = (half_t)(s - (float)h);
            }
            *reinterpret_cast<half8*>(&Ah[srow + i * 64][sseg * 8]) = hh;
            *reinterpret_cast<half8*>(&Al[srow + i * 64][sseg * 8]) = ll;
        }
        if (tid < 160) {
            #pragma unroll
            for (int i = 0; i < 2; ++i) {
                *reinterpret_cast<half8*>(&Bh[brow + i * 40][sseg * 8]) = rBh[i];
                *reinterpret_cast<half8*>(&Bl[brow + i * 40][sseg * 8]) = rBl[i];
            }
        }
        __syncthreads();   // staged chunk visible

        if (kc + 1 < 22) LOAD(kc + 1);   // issue next-chunk loads early

        half8 ah[4], al[4], bh[5], bl[5];
        #pragma unroll
        for (int mf = 0; mf < 4; ++mf) {
            int r = w * 64 + mf * 16 + la;
            ah[mf] = *reinterpret_cast<const half8*>(&Ah[r][lb * 8]);
            al[mf] = *reinterpret_cast<const half8*>(&Al[r][lb * 8]);
        }
        #pragma unroll
        for (int nf = 0; nf < 5; ++nf) {
            int r = nf * 16 + la;
            bh[nf] = *reinterpret_cast<const half8*>(&Bh[r][lb * 8]);
            bl[nf] = *reinterpret_cast<const half8*>(&Bl[r][lb * 8]);
        }
        #pragma unroll
        for (int mf = 0; mf < 4; ++mf)
            #pragma unroll
            for (int nf = 0; nf < 5; ++nf)
                acc[mf][nf] = __builtin_amdgcn_mfma_f32_16x16x32_f16(ah[mf], bh[nf], acc[mf][nf], 0, 0, 0);
        #pragma unroll
        for (int mf = 0; mf < 4; ++mf)
            #pragma unroll
            for (int nf = 0; nf < 5; ++nf)
                acc[mf][nf] = __builtin_amdgcn_mfma_f32_16x16x32_f16(ah[mf], bl[nf], acc[mf][nf], 0, 0, 0);
        #pragma unroll
        for (int mf = 0; mf < 4; ++mf)
            #pragma unroll
            for (int nf = 0; nf < 5; ++nf)
                acc[mf][nf] = __builtin_amdgcn_mfma_f32_16x16x32_f16(al[mf], bh[nf], acc[mf][nf], 0, 0, 0);
    }

    // epilogue: C/D layout col = lane&15, row = (lane>>4)*4 + reg
    float bo[5];
    #pragma unroll
    for (int nf = 0; nf < 5; ++nf) bo[nf] = bin[o0 + nf * 16 + la];

    #pragma unroll
    for (int mf = 0; mf < 4; ++mf) {
        int mbase = m0 + w * 64 + mf * 16 + lb * 4;
        #pragma unroll
        for (int rg = 0; rg < 4; ++rg) {
            int mm = mbase + rg;
            int bb = mm / T_;
            int tt = mm - bb * T_;
            float* yrow = &Y[((size_t)tt * B_ + bb) * NO + o0 + la];
            #pragma unroll
            for (int nf = 0; nf < 5; ++nf)
                yrow[nf * 16] = acc[mf][nf][rg] * INV_S + bo[nf];
        }
    }
}

// ---------------------------------------------------------------------------
// Fallback fp32 GEMM (known-good) if workspace too small for fp16 W arrays.
#define BM 256
#define BN 64
#define BK 16
__global__ __launch_bounds__(256) void dh_gemm_in(
    const float* __restrict__ x, const float* __restrict__ Wt,
    const float* __restrict__ bin, float* __restrict__ Y)
{
    __shared__ float As[BK][BM + 4];
    __shared__ float Bs[BK][BN + 4];
    const int tid = threadIdx.x;
    const int tx = tid & 7;
    const int ty = tid >> 3;
    const int m0 = blockIdx.y * BM;
    const int o0 = blockIdx.x * BN;

    float acc[8][8];
    #pragma unroll
    for (int r = 0; r < 8; ++r)
        #pragma unroll
        for (int c = 0; c < 8; ++c) acc[r][c] = 0.0f;

    const int srow = tid >> 2;
    const int skq  = (tid & 3) << 2;

    for (int k0 = 0; k0 < DIN; k0 += BK) {
        float4 areg[4];
        #pragma unroll
        for (int i = 0; i < 4; ++i) {
            int idx = tid + i * 256;
            int row = idx >> 2;
            int kq  = (idx & 3) << 2;
            int kg  = k0 + kq;
            if (kg < DIN)
                areg[i] = *reinterpret_cast<const float4*>(&x[(size_t)(m0 + row) * DIN + kg]);
            else
                areg[i] = make_float4(0.f, 0.f, 0.f, 0.f);
        }
        float4 breg;
        {
            int kg = k0 + skq;
            int o  = o0 + srow;
            if (kg < DIN && o < NO)
                breg = *reinterpret_cast<const float4*>(&Wt[(size_t)o * DIN + kg]);
            else
                breg = make_float4(0.f, 0.f, 0.f, 0.f);
        }
        __syncthreads();
        #pragma unroll
        for (int i = 0; i < 4; ++i) {
            int idx = tid + i * 256;
            int row = idx >> 2;
            int kq  = (idx & 3) << 2;
            As[kq + 0][row] = areg[i].x;
            As[kq + 1][row] = areg[i].y;
            As[kq + 2][row] = areg[i].z;
            As[kq + 3][row] = areg[i].w;
        }
        Bs[skq + 0][srow] = breg.x;
        Bs[skq + 1][srow] = breg.y;
        Bs[skq + 2][srow] = breg.z;
        Bs[skq + 3][srow] = breg.w;
        __syncthreads();

        #pragma unroll
        for (int k = 0; k < BK; ++k) {
            float a[8], bb[8];
            *reinterpret_cast<float4*>(&a[0])  = *reinterpret_cast<const float4*>(&As[k][ty * 8]);
            *reinterpret_cast<float4*>(&a[4])  = *reinterpret_cast<const float4*>(&As[k][ty * 8 + 4]);
            *reinterpret_cast<float4*>(&bb[0]) = *reinterpret_cast<const float4*>(&Bs[k][tx * 8]);
            *reinterpret_cast<float4*>(&bb[4]) = *reinterpret_cast<const float4*>(&Bs[k][tx * 8 + 4]);
            #pragma unroll
            for (int r = 0; r < 8; ++r)
                #pragma unroll
                for (int c = 0; c < 8; ++c)
                    acc[r][c] = fmaf(a[r], bb[c], acc[r][c]);
        }
    }

    float bo[8];
    #pragma unroll
    for (int c = 0; c < 8; ++c) {
        int o = o0 + tx * 8 + c;
        bo[c] = (o < NO) ? bin[o] : 0.0f;
    }
    const int ob = o0 + tx * 8;
    if (ob < NO) {
        #pragma unroll
        for (int r = 0; r < 8; ++r) {
            int m = m0 + ty * 8 + r;
            int b = m / T_;
            int t = m - b * T_;
            float* yrow = &Y[((size_t)t * B_ + b) * NO];
            float4 v0 = make_float4(acc[r][0] + bo[0], acc[r][1] + bo[1],
                                    acc[r][2] + bo[2], acc[r][3] + bo[3]);
            float4 v1 = make_float4(acc[r][4] + bo[4], acc[r][5] + bo[5],
                                    acc[r][6] + bo[6], acc[r][7] + bo[7]);
            *reinterpret_cast<float4*>(&yrow[ob])     = v0;
            *reinterpret_cast<float4*>(&yrow[ob + 4]) = v1;
        }
    }
}

// ---------------------------------------------------------------------------
// Phase 2: sequential LIF scan over T per (b,h) neuron.
__global__ __launch_bounds__(64) void dh_scan(
    const float* __restrict__ Y, const float* __restrict__ tau_n,
    const float* __restrict__ tau_m, float* __restrict__ counts)
{
    int g = blockIdx.x * 64 + threadIdx.x;   // b*H + h
    int b = g / H_;
    int h = g - b * H_;
    (void)b;
    float beta0 = sigmoidf_(tau_n[h * 2 + 0]);
    float beta1 = sigmoidf_(tau_n[h * 2 + 1]);
    float alpha = sigmoidf_(tau_m[h]);
    float omb0 = 1.0f - beta0, omb1 = 1.0f - beta1, oma = 1.0f - alpha;
    const float2* Yp = reinterpret_cast<const float2*>(Y);

    float v = 0.f, i0 = 0.f, i1 = 0.f, cnt = 0.f;
    #pragma unroll 1
    for (int t0 = 0; t0 < T_; t0 += 10) {
        float2 yb[10];
        #pragma unroll
        for (int j = 0; j < 10; ++j)
            yb[j] = Yp[(size_t)(t0 + j) * (B_ * H_) + g];
        #pragma unroll
        for (int j = 0; j < 10; ++j) {
            i0 = beta0 * i0 + omb0 * yb[j].x;
            i1 = beta1 * i1 + omb1 * yb[j].y;
            float it = i0 + i1;
            v = alpha * v + oma * it;
            if (v >= 1.0f) { v -= 1.0f; cnt += 1.0f; }
        }
    }
    counts[g] = cnt;
}

// Phase 3: out[b][o] = sum_h counts[b][h] * W_out[o][h] + b_out[o]
__global__ __launch_bounds__(64) void dh_out(
    const float* __restrict__ counts, const float* __restrict__ W_out,
    const float* __restrict__ b_out, float* __restrict__ out)
{
    int b = blockIdx.x;
    int o = threadIdx.x;
    if (o >= DOUT) return;
    float acc = b_out[o];
    const float* c = &counts[(size_t)b * H_];
    const float* w = &W_out[(size_t)o * H_];
    #pragma unroll 4
    for (int h = 0; h < H_; ++h)
        acc = fmaf(c[h], w[h], acc);
    out[(size_t)b * DOUT + o] = acc;
}

extern "C" void kernel_launch(void* const* d_in, const int* in_sizes, int n_in,
                              void* d_out, int out_size, void* d_ws, size_t ws_size,
                              hipStream_t stream) {
    const float* x     = (const float*)d_in[0];  // (B,T,DIN)
    const float* W_in  = (const float*)d_in[1];  // (NO,DIN)
    const float* b_in  = (const float*)d_in[2];  // (NO)
    const float* tau_n = (const float*)d_in[3];  // (H,BR)
    const float* tau_m = (const float*)d_in[4];  // (H)
    const float* W_out = (const float*)d_in[5];  // (DOUT,H)
    const float* b_out = (const float*)d_in[6];  // (DOUT)
    float* out = (float*)d_out;                  // (B,DOUT)

    float* Y      = (float*)d_ws;                         // 51.2M floats
    float* counts = Y + (size_t)T_ * B_ * NO;             // 51200 floats

    size_t need_f16 = (size_t)T_ * B_ * NO * 4 + (size_t)B_ * H_ * 4
                    + 2 * ((size_t)NO * KP * 2);

    if (ws_size >= need_f16) {
        half_t* Wh = (half_t*)(counts + (size_t)B_ * H_);
        half_t* Wl = Wh + (size_t)NO * KP;

        cvt_split<<<(NO * 176 + 255) / 256, 256, 0, stream>>>(W_in, Wh, Wl, NO, SW);
        dh_gemm_fused<<<2500, 256, 0, stream>>>(x, Wh, Wl, b_in, Y);
    } else {
        dim3 g1(7, 500);
        dh_gemm_in<<<g1, 256, 0, stream>>>(x, W_in, b_in, Y);
    }

    dh_scan<<<(B_ * H_) / 64, 64, 0, stream>>>(Y, tau_n, tau_m, counts);
    dh_out<<<B_, 64, 0, stream>>>(counts, W_out, b_out, out);
}

// Round 4
// 413.124 us; speedup vs baseline: 2.6363x; 1.0279x over previous
//
#include <hip/hip_runtime.h>

// Problem constants
#define B_   256
#define T_   500
#define DIN  700
#define KP   704      // padded K (for fallback W only)
#define H_   200
#define NO   400      // H*BR
#define DOUT 35
#define NKC  22       // K chunks of 32

typedef _Float16 half_t;
typedef __attribute__((ext_vector_type(8))) _Float16 half8;
typedef __attribute__((ext_vector_type(4))) float floatx4;

#define SX 16.0f      // exact pow2 scale for x
#define SW 4096.0f    // exact pow2 scale for W
#define INV_S (1.0f / 65536.0f)

__device__ __forceinline__ float sigmoidf_(float x) {
    return 1.0f / (1.0f + expf(-x));
}

// ---------------------------------------------------------------------------
// Pre-pass: W -> (hi,lo) fp16 in MFMA-fragment order.
// t = ((kc*25 + nfg)*64 + lane); lane = la + 16*lb.
// value j = W[nfg*16+la][kc*32 + lb*8 + j] (0 beyond col 700), scaled by SW.
__global__ __launch_bounds__(256) void cvt_wfrag(
    const float* __restrict__ W, half_t* __restrict__ Whf, half_t* __restrict__ Wlf)
{
    int t = blockIdx.x * 256 + threadIdx.x;
    if (t >= NKC * 25 * 64) return;
    int lane = t & 63;
    int rest = t >> 6;
    int nfg  = rest % 25;
    int kc   = rest / 25;
    int la = lane & 15, lb = lane >> 4;
    int row = nfg * 16 + la;
    int col = kc * 32 + lb * 8;
    half8 hh, ll;
    #pragma unroll
    for (int j = 0; j < 8; ++j) {
        float v = (col + j < DIN) ? W[(size_t)row * DIN + col + j] : 0.0f;
        float s = v * SW;
        half_t h = (half_t)s;
        hh[j] = h;
        ll[j] = (half_t)(s - (float)h);
    }
    *reinterpret_cast<half8*>(&Whf[(size_t)t * 8]) = hh;
    *reinterpret_cast<half8*>(&Wlf[(size_t)t * 8]) = ll;
}

// ---------------------------------------------------------------------------
// LDS-free split-fp16 MFMA GEMM. One wave owns a 64x80 output tile.
// wave = swizzled_block*4 + w; mt = wave/5 (M tile), nt = wave%5 (N tile).
// A loaded directly from x (fp32) in fragment layout, converted in-register.
// B loaded coalesced from pre-packed Whf/Wlf. No LDS, no barriers.
__global__ __launch_bounds__(256, 2) void dh_gemm_nolds(
    const float* __restrict__ x,
    const half_t* __restrict__ Whf, const half_t* __restrict__ Wlf,
    const float* __restrict__ bin, float* __restrict__ Y)
{
    // XCD-bijective swizzle: nwg=2500, 8 XCDs (q=312, r=4); consecutive L
    // share x panels -> same XCD -> L2 hits on x.
    int p = blockIdx.x;
    int xcd = p & 7, slot = p >> 3;
    int L = (xcd < 4 ? xcd * 313 : 4 * 313 + (xcd - 4) * 312) + slot;

    const int w    = threadIdx.x >> 6;
    const int lane = threadIdx.x & 63;
    const int la   = lane & 15;
    const int lb   = lane >> 4;

    const int wave = L * 4 + w;          // 0..9999
    const int mt = wave / 5, nt = wave - mt * 5;
    const int m0 = mt * 64;              // 64 rows of M
    const int o0 = nt * 80;              // 80 cols of N

    floatx4 acc[4][5];
    #pragma unroll
    for (int mf = 0; mf < 4; ++mf)
        #pragma unroll
        for (int nf = 0; nf < 5; ++nf) {
            floatx4 z = {0.f, 0.f, 0.f, 0.f};
            acc[mf][nf] = z;
        }

    // per-frag A row base (elements)
    size_t arow[4];
    #pragma unroll
    for (int mf = 0; mf < 4; ++mf)
        arow[mf] = (size_t)(m0 + mf * 16 + la) * DIN;
    // B fragment base (halves): ((kc*25 + nt*5+nf)*64 + lane)*8
    const size_t bbase = ((size_t)(nt * 5) * 64 + lane) * 8;

    float4 ra0[4][2], ra1[4][2];
    half8 b0h[5], b0l[5], b1h[5], b1l[5];
    half8 ah[4], al[4];

    auto LOADA = [&](float4 (&ra)[4][2], int kc) {
        const int col = kc * 32 + lb * 8;
        const int c2ofs = (col + 8 <= DIN) ? 4 : (692 - col);  // clamp tail into valid x
        #pragma unroll
        for (int mf = 0; mf < 4; ++mf) {
            const float* ptr = &x[arow[mf] + col];
            ra[mf][0] = *reinterpret_cast<const float4*>(ptr);
            ra[mf][1] = *reinterpret_cast<const float4*>(ptr + c2ofs);
        }
    };
    auto LOADB = [&](half8 (&bh)[5], half8 (&bl)[5], int kc) {
        const size_t kofs = (size_t)kc * 25 * 64 * 8;
        #pragma unroll
        for (int nf = 0; nf < 5; ++nf) {
            size_t idx = bbase + kofs + (size_t)nf * 64 * 8;
            bh[nf] = *reinterpret_cast<const half8*>(&Whf[idx]);
            bl[nf] = *reinterpret_cast<const half8*>(&Wlf[idx]);
        }
    };
    auto CONV = [&](const float4 (&ra)[4][2]) {
        #pragma unroll
        for (int mf = 0; mf < 4; ++mf) {
            float vv[8];
            *reinterpret_cast<float4*>(&vv[0]) = ra[mf][0];
            *reinterpret_cast<float4*>(&vv[4]) = ra[mf][1];
            half8 hh, ll;
            #pragma unroll
            for (int j = 0; j < 8; ++j) {
                float s = vv[j] * SX;
                half_t h = (half_t)s;
                hh[j] = h;
                ll[j] = (half_t)(s - (float)h);
            }
            ah[mf] = hh;
            al[mf] = ll;
        }
    };
    auto MFMAS = [&](const half8 (&bh)[5], const half8 (&bl)[5]) {
        #pragma unroll
        for (int mf = 0; mf < 4; ++mf)
            #pragma unroll
            for (int nf = 0; nf < 5; ++nf)
                acc[mf][nf] = __builtin_amdgcn_mfma_f32_16x16x32_f16(ah[mf], bh[nf], acc[mf][nf], 0, 0, 0);
        #pragma unroll
        for (int mf = 0; mf < 4; ++mf)
            #pragma unroll
            for (int nf = 0; nf < 5; ++nf)
                acc[mf][nf] = __builtin_amdgcn_mfma_f32_16x16x32_f16(ah[mf], bl[nf], acc[mf][nf], 0, 0, 0);
        #pragma unroll
        for (int mf = 0; mf < 4; ++mf)
            #pragma unroll
            for (int nf = 0; nf < 5; ++nf)
                acc[mf][nf] = __builtin_amdgcn_mfma_f32_16x16x32_f16(al[mf], bh[nf], acc[mf][nf], 0, 0, 0);
    };

    LOADA(ra0, 0);
    LOADB(b0h, b0l, 0);
    #pragma unroll 1
    for (int kc2 = 0; kc2 < NKC; kc2 += 2) {
        // even step: prefetch kc2+1, compute kc2
        LOADA(ra1, kc2 + 1);
        LOADB(b1h, b1l, kc2 + 1);
        CONV(ra0);
        MFMAS(b0h, b0l);
        // odd step: prefetch kc2+2 (if any), compute kc2+1
        if (kc2 + 2 < NKC) {
            LOADA(ra0, kc2 + 2);
            LOADB(b0h, b0l, kc2 + 2);
        }
        CONV(ra1);
        MFMAS(b1h, b1l);
    }

    // epilogue: C/D layout col = lane&15, row = (lane>>4)*4 + reg
    float bo[5];
    #pragma unroll
    for (int nf = 0; nf < 5; ++nf) bo[nf] = bin[o0 + nf * 16 + la];

    #pragma unroll
    for (int mf = 0; mf < 4; ++mf) {
        int mbase = m0 + mf * 16 + lb * 4;
        #pragma unroll
        for (int rg = 0; rg < 4; ++rg) {
            int mm = mbase + rg;
            int bb = mm / T_;
            int tt = mm - bb * T_;
            float* yrow = &Y[((size_t)tt * B_ + bb) * NO + o0 + la];
            #pragma unroll
            for (int nf = 0; nf < 5; ++nf)
                yrow[nf * 16] = acc[mf][nf][rg] * INV_S + bo[nf];
        }
    }
}

// ---------------------------------------------------------------------------
// Fallback fp32 GEMM (known-good) if workspace too small.
#define BM 256
#define BN 64
#define BK 16
__global__ __launch_bounds__(256) void dh_gemm_in(
    const float* __restrict__ x, const float* __restrict__ Wt,
    const float* __restrict__ bin, float* __restrict__ Y)
{
    __shared__ float As[BK][BM + 4];
    __shared__ float Bs[BK][BN + 4];
    const int tid = threadIdx.x;
    const int tx = tid & 7;
    const int ty = tid >> 3;
    const int m0 = blockIdx.y * BM;
    const int o0 = blockIdx.x * BN;

    float acc[8][8];
    #pragma unroll
    for (int r = 0; r < 8; ++r)
        #pragma unroll
        for (int c = 0; c < 8; ++c) acc[r][c] = 0.0f;

    const int srow = tid >> 2;
    const int skq  = (tid & 3) << 2;

    for (int k0 = 0; k0 < DIN; k0 += BK) {
        float4 areg[4];
        #pragma unroll
        for (int i = 0; i < 4; ++i) {
            int idx = tid + i * 256;
            int row = idx >> 2;
            int kq  = (idx & 3) << 2;
            int kg  = k0 + kq;
            if (kg < DIN)
                areg[i] = *reinterpret_cast<const float4*>(&x[(size_t)(m0 + row) * DIN + kg]);
            else
                areg[i] = make_float4(0.f, 0.f, 0.f, 0.f);
        }
        float4 breg;
        {
            int kg = k0 + skq;
            int o  = o0 + srow;
            if (kg < DIN && o < NO)
                breg = *reinterpret_cast<const float4*>(&Wt[(size_t)o * DIN + kg]);
            else
                breg = make_float4(0.f, 0.f, 0.f, 0.f);
        }
        __syncthreads();
        #pragma unroll
        for (int i = 0; i < 4; ++i) {
            int idx = tid + i * 256;
            int row = idx >> 2;
            int kq  = (idx & 3) << 2;
            As[kq + 0][row] = areg[i].x;
            As[kq + 1][row] = areg[i].y;
            As[kq + 2][row] = areg[i].z;
            As[kq + 3][row] = areg[i].w;
        }
        Bs[skq + 0][srow] = breg.x;
        Bs[skq + 1][srow] = breg.y;
        Bs[skq + 2][srow] = breg.z;
        Bs[skq + 3][srow] = breg.w;
        __syncthreads();

        #pragma unroll
        for (int k = 0; k < BK; ++k) {
            float a[8], bb[8];
            *reinterpret_cast<float4*>(&a[0])  = *reinterpret_cast<const float4*>(&As[k][ty * 8]);
            *reinterpret_cast<float4*>(&a[4])  = *reinterpret_cast<const float4*>(&As[k][ty * 8 + 4]);
            *reinterpret_cast<float4*>(&bb[0]) = *reinterpret_cast<const float4*>(&Bs[k][tx * 8]);
            *reinterpret_cast<float4*>(&bb[4]) = *reinterpret_cast<const float4*>(&Bs[k][tx * 8 + 4]);
            #pragma unroll
            for (int r = 0; r < 8; ++r)
                #pragma unroll
                for (int c = 0; c < 8; ++c)
                    acc[r][c] = fmaf(a[r], bb[c], acc[r][c]);
        }
    }

    float bo[8];
    #pragma unroll
    for (int c = 0; c < 8; ++c) {
        int o = o0 + tx * 8 + c;
        bo[c] = (o < NO) ? bin[o] : 0.0f;
    }
    const int ob = o0 + tx * 8;
    if (ob < NO) {
        #pragma unroll
        for (int r = 0; r < 8; ++r) {
            int m = m0 + ty * 8 + r;
            int b = m / T_;
            int t = m - b * T_;
            float* yrow = &Y[((size_t)t * B_ + b) * NO];
            float4 v0 = make_float4(acc[r][0] + bo[0], acc[r][1] + bo[1],
                                    acc[r][2] + bo[2], acc[r][3] + bo[3]);
            float4 v1 = make_float4(acc[r][4] + bo[4], acc[r][5] + bo[5],
                                    acc[r][6] + bo[6], acc[r][7] + bo[7]);
            *reinterpret_cast<float4*>(&yrow[ob])     = v0;
            *reinterpret_cast<float4*>(&yrow[ob + 4]) = v1;
        }
    }
}

// ---------------------------------------------------------------------------
// Phase 2: sequential LIF scan over T per (b,h) neuron.
__global__ __launch_bounds__(64) void dh_scan(
    const float* __restrict__ Y, const float* __restrict__ tau_n,
    const float* __restrict__ tau_m, float* __restrict__ counts)
{
    int g = blockIdx.x * 64 + threadIdx.x;   // b*H + h
    int b = g / H_;
    int h = g - b * H_;
    (void)b;
    float beta0 = sigmoidf_(tau_n[h * 2 + 0]);
    float beta1 = sigmoidf_(tau_n[h * 2 + 1]);
    float alpha = sigmoidf_(tau_m[h]);
    float omb0 = 1.0f - beta0, omb1 = 1.0f - beta1, oma = 1.0f - alpha;
    const float2* Yp = reinterpret_cast<const float2*>(Y);

    float v = 0.f, i0 = 0.f, i1 = 0.f, cnt = 0.f;
    #pragma unroll 1
    for (int t0 = 0; t0 < T_; t0 += 10) {
        float2 yb[10];
        #pragma unroll
        for (int j = 0; j < 10; ++j)
            yb[j] = Yp[(size_t)(t0 + j) * (B_ * H_) + g];
        #pragma unroll
        for (int j = 0; j < 10; ++j) {
            i0 = beta0 * i0 + omb0 * yb[j].x;
            i1 = beta1 * i1 + omb1 * yb[j].y;
            float it = i0 + i1;
            v = alpha * v + oma * it;
            if (v >= 1.0f) { v -= 1.0f; cnt += 1.0f; }
        }
    }
    counts[g] = cnt;
}

// Phase 3: out[b][o] = sum_h counts[b][h] * W_out[o][h] + b_out[o]
__global__ __launch_bounds__(64) void dh_out(
    const float* __restrict__ counts, const float* __restrict__ W_out,
    const float* __restrict__ b_out, float* __restrict__ out)
{
    int b = blockIdx.x;
    int o = threadIdx.x;
    if (o >= DOUT) return;
    float acc = b_out[o];
    const float* c = &counts[(size_t)b * H_];
    const float* w = &W_out[(size_t)o * H_];
    #pragma unroll 4
    for (int h = 0; h < H_; ++h)
        acc = fmaf(c[h], w[h], acc);
    out[(size_t)b * DOUT + o] = acc;
}

extern "C" void kernel_launch(void* const* d_in, const int* in_sizes, int n_in,
                              void* d_out, int out_size, void* d_ws, size_t ws_size,
                              hipStream_t stream) {
    const float* x     = (const float*)d_in[0];  // (B,T,DIN)
    const float* W_in  = (const float*)d_in[1];  // (NO,DIN)
    const float* b_in  = (const float*)d_in[2];  // (NO)
    const float* tau_n = (const float*)d_in[3];  // (H,BR)
    const float* tau_m = (const float*)d_in[4];  // (H)
    const float* W_out = (const float*)d_in[5];  // (DOUT,H)
    const float* b_out = (const float*)d_in[6];  // (DOUT)
    float* out = (float*)d_out;                  // (B,DOUT)

    float* Y      = (float*)d_ws;                         // 51.2M floats
    float* counts = Y + (size_t)T_ * B_ * NO;             // 51200 floats

    const size_t nfrag_halves = (size_t)NKC * 25 * 64 * 8;   // 281600
    size_t need = ((size_t)T_ * B_ * NO + (size_t)B_ * H_) * 4
                + 2 * nfrag_halves * 2;

    if (ws_size >= need) {
        half_t* Whf = (half_t*)(counts + (size_t)B_ * H_);
        half_t* Wlf = Whf + nfrag_halves;

        cvt_wfrag<<<(NKC * 25 * 64 + 255) / 256, 256, 0, stream>>>(W_in, Whf, Wlf);
        dh_gemm_nolds<<<2500, 256, 0, stream>>>(x, Whf, Wlf, b_in, Y);
    } else {
        dim3 g1(7, 500);
        dh_gemm_in<<<g1, 256, 0, stream>>>(x, W_in, b_in, Y);
    }

    dh_scan<<<(B_ * H_) / 64, 64, 0, stream>>>(Y, tau_n, tau_m, counts);
    dh_out<<<B_, 64, 0, stream>>>(counts, W_out, b_out, out);
}